// Round 2
// baseline (117986.804 us; speedup 1.0000x reference)
//
#include <hip/hip_runtime.h>
#include <hip/hip_cooperative_groups.h>
#include <cstdint>
#include <cstddef>

namespace cg = cooperative_groups;

#define DI static __device__ __forceinline__

typedef __attribute__((ext_vector_type(8))) short short8;
typedef __attribute__((ext_vector_type(4))) float floatx4;

constexpr int Bz = 8, Tz = 2048, Cz = 768, Hz = 12;
constexpr int G3 = 2304;          // 3C
constexpr int KSEL = 1024;        // T/2 selected tokens
constexpr int DFF = 3072;
constexpr int MTOK = Bz * Tz;     // 16384
constexpr int MSEL = Bz * KSEL;   // 8192
constexpr size_t OUT_E   = (size_t)MTOK * Cz;    // 12582912
constexpr size_t OUT_CNT = OUT_E + (size_t)MTOK; // 12599296
constexpr size_t QKV_STRIDE = (size_t)Bz * Hz * KSEL * 64; // 6291456 elements
constexpr int GRU_WGS = 192;      // 4 hidden cols per WG

DI unsigned short f2bf(float f) {
    unsigned int u = __float_as_uint(f);
    unsigned int r = u + 0x7fffu + ((u >> 16) & 1u);
    return (unsigned short)(r >> 16);
}
DI float gelu_exact(float x) {
    return 0.5f * x * (1.0f + erff(x * 0.70710678118654752440f));
}

// ---------------------------------------------------------------- init
__global__ void init_ws(int* pos, float* d_out) {
    int i = blockIdx.x * 256 + threadIdx.x;
    if (i < MTOK) pos[i] = -1;
    if (i == 0) d_out[OUT_CNT] = 0.0f;
}

// ---------------------------------------------------------------- f32 -> bf16
__global__ void cvt_bf16(const float* __restrict__ src, unsigned short* __restrict__ dst, int n) {
    int i = blockIdx.x * 256 + threadIdx.x;
    int stride = gridDim.x * 256;
    for (; i < n; i += stride) dst[i] = f2bf(src[i]);
}

// ---------------------------------------------------------------- f32 NT GEMM (xi)
// C[m][n] = sum_k A[m][k]*W[n][k] + bias[n].  128x128 tile, BK=16, 8x8 micro.
__global__ __launch_bounds__(256)
void gemm_f32_nt(const float* __restrict__ A, const float* __restrict__ W,
                 const float* __restrict__ bias, float* __restrict__ out,
                 int M, int N, int K) {
    __shared__ float As[16][132];
    __shared__ float Bs[16][132];
    int tid = threadIdx.x;
    int tx = tid & 15, ty = tid >> 4;
    int m0 = blockIdx.y * 128, n0 = blockIdx.x * 128;
    float acc[8][8];
#pragma unroll
    for (int i = 0; i < 8; ++i)
#pragma unroll
        for (int j = 0; j < 8; ++j) acc[i][j] = 0.0f;

    for (int k0 = 0; k0 < K; k0 += 16) {
        __syncthreads();
        for (int f = tid; f < 512; f += 256) {
            int r = f >> 2, c4 = (f & 3) << 2;
            float4 v = *(const float4*)&A[(size_t)(m0 + r) * K + k0 + c4];
            As[c4 + 0][r] = v.x; As[c4 + 1][r] = v.y; As[c4 + 2][r] = v.z; As[c4 + 3][r] = v.w;
            float4 w = *(const float4*)&W[(size_t)(n0 + r) * K + k0 + c4];
            Bs[c4 + 0][r] = w.x; Bs[c4 + 1][r] = w.y; Bs[c4 + 2][r] = w.z; Bs[c4 + 3][r] = w.w;
        }
        __syncthreads();
#pragma unroll 4
        for (int k = 0; k < 16; ++k) {
            float a[8], b[8];
            *(float4*)&a[0] = *(float4*)&As[k][ty * 8];
            *(float4*)&a[4] = *(float4*)&As[k][ty * 8 + 4];
            *(float4*)&b[0] = *(float4*)&Bs[k][tx * 8];
            *(float4*)&b[4] = *(float4*)&Bs[k][tx * 8 + 4];
#pragma unroll
            for (int i = 0; i < 8; ++i)
#pragma unroll
                for (int j = 0; j < 8; ++j) acc[i][j] += a[i] * b[j];
        }
    }
#pragma unroll
    for (int i = 0; i < 8; ++i) {
        int m = m0 + ty * 8 + i;
        int n = n0 + tx * 8;
        float4 o0{acc[i][0] + bias[n + 0], acc[i][1] + bias[n + 1],
                  acc[i][2] + bias[n + 2], acc[i][3] + bias[n + 3]};
        float4 o1{acc[i][4] + bias[n + 4], acc[i][5] + bias[n + 5],
                  acc[i][6] + bias[n + 6], acc[i][7] + bias[n + 7]};
        *(float4*)&out[(size_t)m * N + n] = o0;
        *(float4*)&out[(size_t)m * N + n + 4] = o1;
    }
}

// ---------------------------------------------------------------- GRU scan (cooperative)
__global__ __launch_bounds__(256)
void gru_scan(const float* __restrict__ xi, const float* __restrict__ W_hh,
              const float* __restrict__ b_hh, float* __restrict__ h_rnn) {
    __shared__ float Ws[12][772];
    __shared__ float uni[6208];   // union: hs[8][772] (6176) / part[64][97] (6208)
    __shared__ float hhs[96];
    __shared__ float bhh[12];
    cg::grid_group grid = cg::this_grid();
    int tid = threadIdx.x;
    int c0 = blockIdx.x * 4;

    // persistent W_hh slice: local row j -> global row (j>>2)*768 + c0 + (j&3)
    for (int f = tid; f < 12 * 192; f += 256) {
        int j = f / 192, c4 = (f % 192) * 4;
        *(float4*)&Ws[j][c4] =
            *(const float4*)&W_hh[(size_t)((j >> 2) * Cz + c0 + (j & 3)) * Cz + c4];
    }
    if (tid < 12) bhh[tid] = b_hh[(tid >> 2) * Cz + c0 + (tid & 3)];

    int ci = tid & 3, bb = tid >> 2;   // for gate phase (tid<32)
    float hprev = 0.0f;
    int rg = tid % 3, kc = tid / 3;    // for compute phase (tid<192)
    __syncthreads();

    for (int t = 0; t < Tz; ++t) {
        float* hs = uni;
        if (t == 0) {
            for (int f = tid; f < 8 * 192; f += 256) {
                int b = f / 192, c4 = (f % 192) * 4;
                *(float4*)&hs[b * 772 + c4] = float4{0.f, 0.f, 0.f, 0.f};
            }
        } else {
            for (int f = tid; f < 8 * 192; f += 256) {
                int b = f / 192, c4 = (f % 192) * 4;
                *(float4*)&hs[b * 772 + c4] =
                    *(const float4*)&h_rnn[((size_t)b * Tz + (t - 1)) * Cz + c4];
            }
        }
        __syncthreads();

        float acc[4][8];
        if (tid < 192) {
#pragma unroll
            for (int i = 0; i < 4; ++i)
#pragma unroll
                for (int b = 0; b < 8; ++b) acc[i][b] = 0.0f;
            int kbase = kc * 12;
#pragma unroll
            for (int s = 0; s < 3; ++s) {
                int k = kbase + s * 4;
                float4 wv[4];
#pragma unroll
                for (int i = 0; i < 4; ++i) wv[i] = *(float4*)&Ws[rg * 4 + i][k];
#pragma unroll
                for (int b = 0; b < 8; ++b) {
                    float4 hv = *(float4*)&hs[b * 772 + k];
#pragma unroll
                    for (int i = 0; i < 4; ++i) {
                        acc[i][b] += wv[i].x * hv.x;
                        acc[i][b] += wv[i].y * hv.y;
                        acc[i][b] += wv[i].z * hv.z;
                        acc[i][b] += wv[i].w * hv.w;
                    }
                }
            }
        }
        __syncthreads();   // all hs reads complete before overwriting with partials
        float* part = uni;
        if (tid < 192) {
#pragma unroll
            for (int i = 0; i < 4; ++i)
#pragma unroll
                for (int b = 0; b < 8; ++b)
                    part[kc * 97 + (rg * 4 + i) * 8 + b] = acc[i][b];
        }
        __syncthreads();
        if (tid < 96) {
            float s = 0.0f;
            for (int q = 0; q < 64; ++q) s += part[q * 97 + tid];
            hhs[tid] = s + bhh[tid >> 3];
        }
        __syncthreads();
        if (tid < 32) {
            float hr = hhs[(0 + ci) * 8 + bb];
            float hz = hhs[(4 + ci) * 8 + bb];
            float hn = hhs[(8 + ci) * 8 + bb];
            int c = c0 + ci;
            const float* xrow = xi + ((size_t)bb * Tz + t) * G3;
            float xr = xrow[c], xz = xrow[Cz + c], xn = xrow[2 * Cz + c];
            float r = 1.0f / (1.0f + expf(-(xr + hr)));
            float z = 1.0f / (1.0f + expf(-(xz + hz)));
            float n = tanhf(xn + r * hn);
            float hnew = (1.0f - z) * n + z * hprev;
            hprev = hnew;
            h_rnn[((size_t)bb * Tz + t) * Cz + c] = hnew;
        }
        __threadfence();   // release h(t) writes to device scope
        grid.sync();
        __threadfence();   // acquire: next step's h reads see all WGs' writes
    }
}

// ---------------------------------------------------------------- gate MLP / energy
__global__ __launch_bounds__(256)
void gate_energy(const float* __restrict__ h_rnn, const float* __restrict__ w1,
                 const float* __restrict__ b1, const float* __restrict__ w2,
                 const float* __restrict__ b2v, float* __restrict__ energy_ws,
                 float* __restrict__ d_out) {
    int wid = threadIdx.x >> 6, lane = threadIdx.x & 63;
    int token = blockIdx.x * 4 + wid;
    const float* hrow = h_rnn + (size_t)token * Cz;
    float hid[32];
#pragma unroll
    for (int u = 0; u < 32; ++u) hid[u] = 0.0f;
#pragma unroll
    for (int j = 0; j < 12; ++j) {
        int c = lane + 64 * j;
        float x = hrow[c];
#pragma unroll
        for (int u = 0; u < 32; ++u) hid[u] += x * w1[u * Cz + c];
    }
#pragma unroll
    for (int m = 1; m <= 32; m <<= 1) {
#pragma unroll
        for (int u = 0; u < 32; ++u) hid[u] += __shfl_xor(hid[u], m, 64);
    }
    float uacc = 0.0f;
#pragma unroll
    for (int u = 0; u < 32; ++u) uacc += tanhf(hid[u] + b1[u]) * w2[u];
    float e = 1.0f / (1.0f + expf(-(uacc + b2v[0])));
    if (lane == 0) {
        energy_ws[token] = e;
        d_out[OUT_E + token] = e;
        if (e > 0.5f) atomicAdd(&d_out[OUT_CNT], 1.0f);
    }
}

// ---------------------------------------------------------------- top-k via bitonic sort
__global__ __launch_bounds__(256)
void topk_kernel(const float* __restrict__ energy, int* __restrict__ idx) {
    __shared__ unsigned long long keys[2048];
    __shared__ unsigned int sel[1024];
    int tid = threadIdx.x, b = blockIdx.x;
    for (int i = tid; i < 2048; i += 256) {
        unsigned int u = __float_as_uint(energy[b * Tz + i]);  // energies > 0
        keys[i] = ((unsigned long long)(~u) << 32) | (unsigned int)i;
    }
    for (int k2 = 2; k2 <= 2048; k2 <<= 1) {
        for (int j = k2 >> 1; j > 0; j >>= 1) {
            __syncthreads();
            for (int i = tid; i < 2048; i += 256) {
                int ixj = i ^ j;
                if (ixj > i) {
                    bool up = ((i & k2) == 0);
                    unsigned long long a = keys[i], c = keys[ixj];
                    if ((a > c) == up) { keys[i] = c; keys[ixj] = a; }
                }
            }
        }
    }
    __syncthreads();
    for (int i = tid; i < 1024; i += 256) sel[i] = (unsigned int)(keys[i] & 0xffffffffu);
    for (int k2 = 2; k2 <= 1024; k2 <<= 1) {
        for (int j = k2 >> 1; j > 0; j >>= 1) {
            __syncthreads();
            for (int i = tid; i < 1024; i += 256) {
                int ixj = i ^ j;
                if (ixj > i) {
                    bool up = ((i & k2) == 0);
                    unsigned int a = sel[i], c = sel[ixj];
                    if ((a > c) == up) { sel[i] = c; sel[ixj] = a; }
                }
            }
        }
    }
    __syncthreads();
    for (int i = tid; i < 1024; i += 256) idx[b * KSEL + i] = (int)sel[i];
}

// ---------------------------------------------------------------- gather + bf16
__global__ void gather_sel(const float* __restrict__ h_rnn, const int* __restrict__ idx,
                           unsigned short* __restrict__ x_sel) {
    int i4 = blockIdx.x * 256 + threadIdx.x;   // MSEL*192 total
    int r = i4 / 192, c4 = (i4 % 192) * 4;
    int b = r >> 10;
    float4 v = *(const float4*)&h_rnn[((size_t)(b << 11) + idx[r]) * Cz + c4];
    ushort4 o;
    o.x = f2bf(v.x); o.y = f2bf(v.y); o.z = f2bf(v.z); o.w = f2bf(v.w);
    *(ushort4*)&x_sel[(size_t)r * Cz + c4] = o;
}

__global__ void scatter_pos(const int* __restrict__ idx, int* __restrict__ pos) {
    int i = blockIdx.x * 256 + threadIdx.x;
    if (i < MSEL) {
        int b = i >> 10;
        pos[(b << 11) + idx[i]] = i & 1023;
    }
}

// ---------------------------------------------------------------- bf16 MFMA GEMM (NT)
// C[m][n] = sum_k A[m][k]*W[n][k]; EPI: 0 f32+bias, 1 qkv-scatter bf16,
// 2 gelu->bf16, 3 f32 = acc+bias+res (final output)
template <int EPI>
__global__ __launch_bounds__(256)
void gemm_bf16(const unsigned short* __restrict__ A, const unsigned short* __restrict__ W,
               const float* __restrict__ bias, float* __restrict__ out_f,
               unsigned short* __restrict__ out_b, const float* __restrict__ res,
               int M, int N, int K) {
    __shared__ unsigned short As[128][72];
    __shared__ unsigned short Bs[128][72];
    int tid = threadIdx.x;
    int wid = tid >> 6, lane = tid & 63;
    int quad = lane >> 4, l16 = lane & 15;
    int wm = (wid >> 1) * 64, wn = (wid & 1) * 64;
    int m0 = blockIdx.y * 128, n0 = blockIdx.x * 128;

    floatx4 acc[4][4];
#pragma unroll
    for (int i = 0; i < 4; ++i)
#pragma unroll
        for (int j = 0; j < 4; ++j) acc[i][j] = floatx4{0.f, 0.f, 0.f, 0.f};

    for (int k0 = 0; k0 < K; k0 += 64) {
        __syncthreads();
        for (int f = tid; f < 1024; f += 256) {
            int r = f >> 3, cc = (f & 7) * 8;
            *(uint4*)&As[r][cc] = *(const uint4*)&A[(size_t)(m0 + r) * K + k0 + cc];
            *(uint4*)&Bs[r][cc] = *(const uint4*)&W[(size_t)(n0 + r) * K + k0 + cc];
        }
        __syncthreads();
#pragma unroll
        for (int kh = 0; kh < 2; ++kh) {
            short8 af[4], bf[4];
#pragma unroll
            for (int i = 0; i < 4; ++i)
                af[i] = *(const short8*)&As[wm + i * 16 + l16][kh * 32 + quad * 8];
#pragma unroll
            for (int i = 0; i < 4; ++i)
                bf[i] = *(const short8*)&Bs[wn + i * 16 + l16][kh * 32 + quad * 8];
#pragma unroll
            for (int mi = 0; mi < 4; ++mi)
#pragma unroll
                for (int ni = 0; ni < 4; ++ni)
                    acc[mi][ni] = __builtin_amdgcn_mfma_f32_16x16x32_bf16(
                        af[mi], bf[ni], acc[mi][ni], 0, 0, 0);
        }
    }

#pragma unroll
    for (int mi = 0; mi < 4; ++mi) {
#pragma unroll
        for (int ni = 0; ni < 4; ++ni) {
            int n = n0 + wn + ni * 16 + l16;
            float bv = bias[n];
#pragma unroll
            for (int r = 0; r < 4; ++r) {
                int m = m0 + wm + mi * 16 + quad * 4 + r;
                float val = acc[mi][ni][r] + bv;
                if constexpr (EPI == 0) {
                    out_f[(size_t)m * N + n] = val;
                } else if constexpr (EPI == 1) {
                    int b = m >> 10, kk = m & 1023;
                    int which = n / Cz;
                    int rr = n - which * Cz;
                    int h = rr >> 6, d = rr & 63;
                    out_b[(size_t)which * QKV_STRIDE +
                          (((size_t)(b * Hz + h) * KSEL + kk) << 6) + d] = f2bf(val);
                } else if constexpr (EPI == 2) {
                    out_b[(size_t)m * N + n] = f2bf(gelu_exact(val));
                } else {
                    out_f[(size_t)m * N + n] = val + res[(size_t)m * N + n];
                }
            }
        }
    }
}

// ---------------------------------------------------------------- flash attention
__global__ __launch_bounds__(256)
void flash_attn(const unsigned short* __restrict__ qkvb, unsigned short* __restrict__ y_rows) {
    __shared__ unsigned short Qs[64][88];
    __shared__ unsigned short Ks[64][88];
    __shared__ unsigned short Vt[64][88];
    __shared__ unsigned short Ps[4][16][88];
    int tid = threadIdx.x;
    int wid = tid >> 6, lane = tid & 63;
    int quad = lane >> 4, l16 = lane & 15;
    int wq0 = wid * 16;
    int qt = blockIdx.x, bh = blockIdx.y;
    int q0 = qt * 64;
    const unsigned short* Qg = qkvb + ((size_t)bh * KSEL << 6);
    const unsigned short* Kg = Qg + QKV_STRIDE;
    const unsigned short* Vg = Qg + 2 * QKV_STRIDE;
    int b = bh / Hz, h = bh - b * Hz;

    for (int f = tid; f < 512; f += 256) {
        int r = f >> 3, cc = (f & 7) * 8;
        *(uint4*)&Qs[r][cc] = *(const uint4*)&Qg[(size_t)(q0 + r) * 64 + cc];
    }

    float m_i[4], l_i[4];
    floatx4 oacc[4];
#pragma unroll
    for (int r = 0; r < 4; ++r) { m_i[r] = -3.0e38f; l_i[r] = 0.0f; }
#pragma unroll
    for (int d = 0; d < 4; ++d) oacc[d] = floatx4{0.f, 0.f, 0.f, 0.f};

    for (int jt = 0; jt <= qt; ++jt) {
        int k0 = jt * 64;
        __syncthreads();
        for (int f = tid; f < 512; f += 256) {
            int r = f >> 3, cc = (f & 7) * 8;
            *(uint4*)&Ks[r][cc] = *(const uint4*)&Kg[(size_t)(k0 + r) * 64 + cc];
            uint4 v = *(const uint4*)&Vg[(size_t)(k0 + r) * 64 + cc];
            const unsigned short* pv = (const unsigned short*)&v;
#pragma unroll
            for (int e = 0; e < 8; ++e) Vt[cc + e][r] = pv[e];
        }
        __syncthreads();

        floatx4 sacc[4];
#pragma unroll
        for (int ni = 0; ni < 4; ++ni) sacc[ni] = floatx4{0.f, 0.f, 0.f, 0.f};
#pragma unroll
        for (int kh = 0; kh < 2; ++kh) {
            short8 aq = *(const short8*)&Qs[wq0 + l16][kh * 32 + quad * 8];
#pragma unroll
            for (int ni = 0; ni < 4; ++ni) {
                short8 bk = *(const short8*)&Ks[ni * 16 + l16][kh * 32 + quad * 8];
                sacc[ni] = __builtin_amdgcn_mfma_f32_16x16x32_bf16(aq, bk, sacc[ni], 0, 0, 0);
            }
        }
        // scale + causal mask
#pragma unroll
        for (int ni = 0; ni < 4; ++ni) {
            int kg = k0 + ni * 16 + l16;
#pragma unroll
            for (int r = 0; r < 4; ++r) {
                int qg = q0 + wq0 + quad * 4 + r;
                float s = sacc[ni][r] * 0.125f;
                sacc[ni][r] = (kg > qg) ? -1.0e30f : s;
            }
        }
        // online softmax per q-row
        float alpha[4];
#pragma unroll
        for (int r = 0; r < 4; ++r) {
            float mx = sacc[0][r];
#pragma unroll
            for (int ni = 1; ni < 4; ++ni) mx = fmaxf(mx, sacc[ni][r]);
#pragma unroll
            for (int m = 1; m <= 8; m <<= 1) mx = fmaxf(mx, __shfl_xor(mx, m, 64));
            float mn = fmaxf(m_i[r], mx);
            alpha[r] = expf(m_i[r] - mn);
            float rs = 0.0f;
#pragma unroll
            for (int ni = 0; ni < 4; ++ni) {
                float p = expf(sacc[ni][r] - mn);
                sacc[ni][r] = p;
                rs += p;
            }
#pragma unroll
            for (int m = 1; m <= 8; m <<= 1) rs += __shfl_xor(rs, m, 64);
            m_i[r] = mn;
            l_i[r] = l_i[r] * alpha[r] + rs;
        }
        // store P (bf16) in A-operand friendly layout
#pragma unroll
        for (int ni = 0; ni < 4; ++ni)
#pragma unroll
            for (int r = 0; r < 4; ++r)
                Ps[wid][quad * 4 + r][ni * 16 + l16] = f2bf(sacc[ni][r]);
        // rescale O accumulator
#pragma unroll
        for (int d = 0; d < 4; ++d)
#pragma unroll
            for (int r = 0; r < 4; ++r) oacc[d][r] *= alpha[r];
        // PV
#pragma unroll
        for (int kh = 0; kh < 2; ++kh) {
            short8 ap = *(const short8*)&Ps[wid][l16][kh * 32 + quad * 8];
#pragma unroll
            for (int d = 0; d < 4; ++d) {
                short8 bv = *(const short8*)&Vt[d * 16 + l16][kh * 32 + quad * 8];
                oacc[d] = __builtin_amdgcn_mfma_f32_16x16x32_bf16(ap, bv, oacc[d], 0, 0, 0);
            }
        }
    }
    // normalize + write y_rows bf16 [MSEL x C] at col h*64+d
#pragma unroll
    for (int r = 0; r < 4; ++r) {
        float inv = 1.0f / l_i[r];
        size_t row = (size_t)b * KSEL + q0 + wq0 + quad * 4 + r;
#pragma unroll
        for (int d = 0; d < 4; ++d)
            y_rows[row * Cz + h * 64 + d * 16 + l16] = f2bf(oacc[d][r] * inv);
    }
}

// ---------------------------------------------------------------- scatter + LayerNorm (in-place on h)
__global__ __launch_bounds__(256)
void ln_fuse(float* h, const float* __restrict__ proj_out,
             const int* __restrict__ pos, const float* __restrict__ energy_ws,
             const float* __restrict__ ln_g, const float* __restrict__ ln_b,
             unsigned short* __restrict__ h_ln_bf) {
    int wid = threadIdx.x >> 6, lane = threadIdx.x & 63;
    int token = blockIdx.x * 4 + wid;
    int b = token >> 11;
    float* hrow = h + (size_t)token * Cz;
    int p = pos[token];
    float gsc = (p >= 0) ? energy_ws[token] : 0.0f;
    const float* prow = proj_out + ((size_t)(b << 10) + (p >= 0 ? p : 0)) * Cz;
    float x[12], s1 = 0.0f, s2 = 0.0f;
#pragma unroll
    for (int j = 0; j < 12; ++j) {
        int c = lane + 64 * j;
        float v = hrow[c] + gsc * prow[c];
        x[j] = v;
        s1 += v;
        s2 += v * v;
    }
#pragma unroll
    for (int m = 1; m <= 32; m <<= 1) {
        s1 += __shfl_xor(s1, m, 64);
        s2 += __shfl_xor(s2, m, 64);
    }
    float mu = s1 * (1.0f / 768.0f);
    float var = s2 * (1.0f / 768.0f) - mu * mu;
    var = fmaxf(var, 0.0f);
    float rs = 1.0f / sqrtf(var + 1e-5f);
#pragma unroll
    for (int j = 0; j < 12; ++j) {
        int c = lane + 64 * j;
        float y = (x[j] - mu) * rs * ln_g[c] + ln_b[c];
        hrow[c] = y;                                   // in-place: h becomes h_ln
        h_ln_bf[(size_t)token * Cz + c] = f2bf(y);
    }
}

// ---------------------------------------------------------------- launch
extern "C" void kernel_launch(void* const* d_in, const int* in_sizes, int n_in,
                              void* d_out, int out_size, void* d_ws, size_t ws_size,
                              hipStream_t stream) {
    (void)in_sizes; (void)n_in; (void)out_size; (void)ws_size;
    const float* x      = (const float*)d_in[0];
    const float* W_ih   = (const float*)d_in[1];
    const float* W_hh   = (const float*)d_in[2];
    const float* b_ih   = (const float*)d_in[3];
    const float* b_hh   = (const float*)d_in[4];
    const float* gw1    = (const float*)d_in[5];
    const float* gb1    = (const float*)d_in[6];
    const float* gw2    = (const float*)d_in[7];
    const float* gb2    = (const float*)d_in[8];
    const float* qkv_w  = (const float*)d_in[9];
    const float* qkv_b  = (const float*)d_in[10];
    const float* proj_w = (const float*)d_in[11];
    const float* proj_b = (const float*)d_in[12];
    const float* ln_g   = (const float*)d_in[13];
    const float* ln_b   = (const float*)d_in[14];
    const float* ffn_w1 = (const float*)d_in[15];
    const float* ffn_b1 = (const float*)d_in[16];
    const float* ffn_w2 = (const float*)d_in[17];
    const float* ffn_b2 = (const float*)d_in[18];
    float* out = (float*)d_out;

    // -------- workspace layout (lifetime-aliased; peak ~215.6 MB) --------
    char* ws = (char*)d_ws;
    // Region R1 [0, 150,994,944): xi f32 during GRU; then post-selection chain.
    float* xi               = (float*)ws;
    unsigned short* x_sel   = (unsigned short*)ws;                 // [0, 12.6M)
    unsigned short* qkvb    = (unsigned short*)(ws + 13631488);    // [13.6M, 51.4M)
    unsigned short* y_rows  = (unsigned short*)ws;                 // [0, 12.6M)
    float* proj_out         = (float*)(ws + 52428800);             // [52.4M, 77.6M)
    unsigned short* h_ln_bf = (unsigned short*)ws;                 // [0, 25.2M)
    unsigned short* a1      = (unsigned short*)(ws + 25165824);    // [25.2M, 125.8M)
    // Region R2: h_rnn f32 (becomes h_ln in-place after ln_fuse)
    float* h_rnn     = (float*)(ws + 150994944);                   // 50,331,648 B
    float* energy_ws = (float*)(ws + 201326592);                   // 65,536 B
    int*   idx       = (int*)(ws + 201392128);                     // 32,768 B
    int*   pos       = (int*)(ws + 201424896);                     // 65,536 B
    unsigned short* qkv_w_b  = (unsigned short*)(ws + 201490432);  // 3,538,944 B
    unsigned short* proj_w_b = (unsigned short*)(ws + 205029376);  // 1,179,648 B
    unsigned short* w1_b     = (unsigned short*)(ws + 206209024);  // 4,718,592 B
    unsigned short* w2_b     = (unsigned short*)(ws + 210927616);  // 4,718,592 B
    // end: 215,646,208 B

    init_ws<<<64, 256, 0, stream>>>(pos, out);
    cvt_bf16<<<2048, 256, 0, stream>>>(qkv_w, qkv_w_b, G3 * Cz);
    cvt_bf16<<<2048, 256, 0, stream>>>(proj_w, proj_w_b, Cz * Cz);
    cvt_bf16<<<2048, 256, 0, stream>>>(ffn_w1, w1_b, DFF * Cz);
    cvt_bf16<<<2048, 256, 0, stream>>>(ffn_w2, w2_b, Cz * DFF);

    gemm_f32_nt<<<dim3(G3 / 128, MTOK / 128), 256, 0, stream>>>(x, W_ih, b_ih, xi,
                                                                MTOK, G3, Cz);
    {
        const float* xi_c = xi;
        void* gru_args[] = {(void*)&xi_c, (void*)&W_hh, (void*)&b_hh, (void*)&h_rnn};
        hipLaunchCooperativeKernel((void*)gru_scan, dim3(GRU_WGS), dim3(256),
                                   gru_args, 0, stream);
    }
    gate_energy<<<MTOK / 4, 256, 0, stream>>>(h_rnn, gw1, gb1, gw2, gb2, energy_ws, out);
    topk_kernel<<<Bz, 256, 0, stream>>>(energy_ws, idx);
    scatter_pos<<<MSEL / 256, 256, 0, stream>>>(idx, pos);
    gather_sel<<<MSEL * 192 / 256, 256, 0, stream>>>(h_rnn, idx, x_sel);

    gemm_bf16<1><<<dim3(G3 / 128, MSEL / 128), 256, 0, stream>>>(
        x_sel, qkv_w_b, qkv_b, nullptr, qkvb, nullptr, MSEL, G3, Cz);
    flash_attn<<<dim3(16, Bz * Hz), 256, 0, stream>>>(qkvb, y_rows);
    gemm_bf16<0><<<dim3(Cz / 128, MSEL / 128), 256, 0, stream>>>(
        y_rows, proj_w_b, proj_b, proj_out, nullptr, nullptr, MSEL, Cz, Cz);
    ln_fuse<<<MTOK / 4, 256, 0, stream>>>(h_rnn, proj_out, pos, energy_ws, ln_g, ln_b,
                                          h_ln_bf);
    gemm_bf16<2><<<dim3(DFF / 128, MTOK / 128), 256, 0, stream>>>(
        h_ln_bf, w1_b, ffn_b1, nullptr, a1, nullptr, MTOK, DFF, Cz);
    gemm_bf16<3><<<dim3(Cz / 128, MTOK / 128), 256, 0, stream>>>(
        a1, w2_b, ffn_b2, out, nullptr, h_rnn, MTOK, Cz, DFF);
}

// Round 4
// 74987.640 us; speedup vs baseline: 1.5734x; 1.5734x over previous
//
#include <hip/hip_runtime.h>
#include <cstdint>
#include <cstddef>

#define DI static __device__ __forceinline__

typedef __attribute__((ext_vector_type(8))) short short8;
typedef __attribute__((ext_vector_type(4))) float floatx4;

constexpr int Bz = 8, Tz = 2048, Cz = 768, Hz = 12;
constexpr int G3 = 2304;          // 3C
constexpr int KSEL = 1024;        // T/2 selected tokens
constexpr int DFF = 3072;
constexpr int MTOK = Bz * Tz;     // 16384
constexpr int MSEL = Bz * KSEL;   // 8192
constexpr size_t OUT_E   = (size_t)MTOK * Cz;    // 12582912
constexpr size_t OUT_CNT = OUT_E + (size_t)MTOK; // 12599296
constexpr size_t QKV_STRIDE = (size_t)Bz * Hz * KSEL * 64; // 6291456 elements
constexpr int WPG = 48;           // workgroups per batch-group (16 cols each)
constexpr int GRU_WGS = Bz * WPG; // 384  (<= 2 blocks/CU * 256 CUs, all resident)

DI unsigned short f2bf(float f) {
    unsigned int u = __float_as_uint(f);
    unsigned int r = u + 0x7fffu + ((u >> 16) & 1u);
    return (unsigned short)(r >> 16);
}
DI float gelu_exact(float x) {
    return 0.5f * x * (1.0f + erff(x * 0.70710678118654752440f));
}

// ---------------------------------------------------------------- init
__global__ void init_ws(int* pos, int* cnt, float* d_out) {
    int i = blockIdx.x * 256 + threadIdx.x;
    if (i < MTOK) pos[i] = -1;
    if (i < Bz * Tz) cnt[i] = 0;
    if (i == 0) d_out[OUT_CNT] = 0.0f;
}

// ---------------------------------------------------------------- f32 -> bf16
__global__ void cvt_bf16(const float* __restrict__ src, unsigned short* __restrict__ dst, int n) {
    int i = blockIdx.x * 256 + threadIdx.x;
    int stride = gridDim.x * 256;
    for (; i < n; i += stride) dst[i] = f2bf(src[i]);
}

// ---------------------------------------------------------------- f32 NT GEMM (xi)
__global__ __launch_bounds__(256)
void gemm_f32_nt(const float* __restrict__ A, const float* __restrict__ W,
                 const float* __restrict__ bias, float* __restrict__ out,
                 int M, int N, int K) {
    __shared__ float As[16][132];
    __shared__ float Bs[16][132];
    int tid = threadIdx.x;
    int tx = tid & 15, ty = tid >> 4;
    int m0 = blockIdx.y * 128, n0 = blockIdx.x * 128;
    float acc[8][8];
#pragma unroll
    for (int i = 0; i < 8; ++i)
#pragma unroll
        for (int j = 0; j < 8; ++j) acc[i][j] = 0.0f;

    for (int k0 = 0; k0 < K; k0 += 16) {
        __syncthreads();
        for (int f = tid; f < 512; f += 256) {
            int r = f >> 2, c4 = (f & 3) << 2;
            float4 v = *(const float4*)&A[(size_t)(m0 + r) * K + k0 + c4];
            As[c4 + 0][r] = v.x; As[c4 + 1][r] = v.y; As[c4 + 2][r] = v.z; As[c4 + 3][r] = v.w;
            float4 w = *(const float4*)&W[(size_t)(n0 + r) * K + k0 + c4];
            Bs[c4 + 0][r] = w.x; Bs[c4 + 1][r] = w.y; Bs[c4 + 2][r] = w.z; Bs[c4 + 3][r] = w.w;
        }
        __syncthreads();
#pragma unroll 4
        for (int k = 0; k < 16; ++k) {
            float a[8], b[8];
            *(float4*)&a[0] = *(float4*)&As[k][ty * 8];
            *(float4*)&a[4] = *(float4*)&As[k][ty * 8 + 4];
            *(float4*)&b[0] = *(float4*)&Bs[k][tx * 8];
            *(float4*)&b[4] = *(float4*)&Bs[k][tx * 8 + 4];
#pragma unroll
            for (int i = 0; i < 8; ++i)
#pragma unroll
                for (int j = 0; j < 8; ++j) acc[i][j] += a[i] * b[j];
        }
    }
#pragma unroll
    for (int i = 0; i < 8; ++i) {
        int m = m0 + ty * 8 + i;
        int n = n0 + tx * 8;
        float4 o0{acc[i][0] + bias[n + 0], acc[i][1] + bias[n + 1],
                  acc[i][2] + bias[n + 2], acc[i][3] + bias[n + 3]};
        float4 o1{acc[i][4] + bias[n + 4], acc[i][5] + bias[n + 5],
                  acc[i][6] + bias[n + 6], acc[i][7] + bias[n + 7]};
        *(float4*)&out[(size_t)m * N + n] = o0;
        *(float4*)&out[(size_t)m * N + n + 4] = o1;
    }
}

// ---------------------------------------------------------------- GRU scan
// PLAIN launch (no cooperative API): 384 WGs, launch_bounds(256,2) caps VGPR
// at 256 -> >=2 blocks/CU -> 512 slots >= 384 -> all WGs resident.
// 8 independent batch groups x 48 WGs; each WG owns 16 hidden cols, its
// W_hh slice (48 rows x 768) in registers (144 VGPR/thread).
// Per-group per-step barrier: agent-scope atomic counter per (g,t);
// acquire fence executed by EVERY thread after the barrier.
__global__ __launch_bounds__(256, 2)
void gru_scan(const float* __restrict__ xi, const float* __restrict__ W_hh,
              const float* __restrict__ b_hh, float* __restrict__ h_rnn,
              int* __restrict__ cnt) {
    __shared__ float hs[768];        // h(t-1) for this batch
    __shared__ float part[48][17];   // k-chunk partials
    __shared__ float hh[48];
    __shared__ float bhh[48];
    int tid = threadIdx.x;
    int g = blockIdx.x / WPG;        // batch
    int w = blockIdx.x % WPG;        // col group
    int c0 = w * 16;
    int rowgrp = tid & 15;           // owns local rows lr0..lr0+2
    int kc = tid >> 4;               // k chunk (48 wide), 0..15
    int lr0 = rowgrp * 3;

    // W_hh slice -> registers. local row lr: gate=lr>>4, col=lr&15.
    float4 Wreg[3][12];
#pragma unroll
    for (int i = 0; i < 3; ++i) {
        int lr = lr0 + i;
        size_t grow = (size_t)((lr >> 4) * Cz + c0 + (lr & 15));
        const float4* src = (const float4*)&W_hh[grow * Cz + kc * 48];
#pragma unroll
        for (int q = 0; q < 12; ++q) Wreg[i][q] = src[q];
    }
    if (tid < 48) bhh[tid] = b_hh[(tid >> 4) * Cz + c0 + (tid & 15)];
    int* mycnt = cnt + g * Tz;
    __syncthreads();

    for (int t = 0; t < Tz; ++t) {
        // prefetch xi for this step (wave 0 only; consumed after the matvec)
        float xr = 0.f, xz = 0.f, xn = 0.f;
        if (tid < 16) {
            const float* xrow = xi + ((size_t)g * Tz + t) * G3 + c0 + tid;
            xr = xrow[0]; xz = xrow[Cz]; xn = xrow[2 * Cz];
        }
        // stage h(t-1) into LDS
        if (tid < 192) {
            float4 v;
            if (t == 0) v = float4{0.f, 0.f, 0.f, 0.f};
            else v = *(const float4*)&h_rnn[((size_t)g * Tz + (t - 1)) * Cz + tid * 4];
            *(float4*)&hs[tid * 4] = v;
        }
        __syncthreads();

        // partial matvec: 3 rows x 48 k per thread
        float acc0 = 0.f, acc1 = 0.f, acc2 = 0.f;
        const float4* hv = (const float4*)&hs[kc * 48];
#pragma unroll
        for (int q = 0; q < 12; ++q) {
            float4 h4 = hv[q];
            acc0 += Wreg[0][q].x * h4.x + Wreg[0][q].y * h4.y +
                    Wreg[0][q].z * h4.z + Wreg[0][q].w * h4.w;
            acc1 += Wreg[1][q].x * h4.x + Wreg[1][q].y * h4.y +
                    Wreg[1][q].z * h4.z + Wreg[1][q].w * h4.w;
            acc2 += Wreg[2][q].x * h4.x + Wreg[2][q].y * h4.y +
                    Wreg[2][q].z * h4.z + Wreg[2][q].w * h4.w;
        }
        part[lr0 + 0][kc] = acc0;
        part[lr0 + 1][kc] = acc1;
        part[lr0 + 2][kc] = acc2;
        __syncthreads();
        if (tid < 48) {
            float s = 0.f;
#pragma unroll
            for (int q = 0; q < 16; ++q) s += part[tid][q];
            hh[tid] = s + bhh[tid];
        }
        __syncthreads();
        if (tid < 16) {
            float hr = hh[tid], hz = hh[16 + tid], hn = hh[32 + tid];
            float hp = hs[c0 + tid];
            float r = 1.0f / (1.0f + expf(-(xr + hr)));
            float z = 1.0f / (1.0f + expf(-(xz + hz)));
            float n = tanhf(xn + r * hn);
            float hnew = (1.0f - z) * n + z * hp;
            h_rnn[((size_t)g * Tz + t) * Cz + c0 + tid] = hnew;
        }
        // barrier: release by wave 0 (same wave as the h stores), then
        // acquire fence by EVERY thread so each wave's next-step loads are
        // ordered after an invalidate in its own instruction stream.
        if (tid == 0) {
            __threadfence();         // release: drain stores, writeback L2
            __hip_atomic_fetch_add(mycnt + t, 1, __ATOMIC_RELEASE,
                                   __HIP_MEMORY_SCOPE_AGENT);
            while (__hip_atomic_load(mycnt + t, __ATOMIC_RELAXED,
                                     __HIP_MEMORY_SCOPE_AGENT) < WPG)
                __builtin_amdgcn_s_sleep(1);
        }
        __syncthreads();
        __threadfence();             // acquire (all threads): invalidate L1/L2
    }
}

// ---------------------------------------------------------------- gate MLP / energy
__global__ __launch_bounds__(256)
void gate_energy(const float* __restrict__ h_rnn, const float* __restrict__ w1,
                 const float* __restrict__ b1, const float* __restrict__ w2,
                 const float* __restrict__ b2v, float* __restrict__ energy_ws,
                 float* __restrict__ d_out) {
    int wid = threadIdx.x >> 6, lane = threadIdx.x & 63;
    int token = blockIdx.x * 4 + wid;
    const float* hrow = h_rnn + (size_t)token * Cz;
    float hid[32];
#pragma unroll
    for (int u = 0; u < 32; ++u) hid[u] = 0.0f;
#pragma unroll
    for (int j = 0; j < 12; ++j) {
        int c = lane + 64 * j;
        float x = hrow[c];
#pragma unroll
        for (int u = 0; u < 32; ++u) hid[u] += x * w1[u * Cz + c];
    }
#pragma unroll
    for (int m = 1; m <= 32; m <<= 1) {
#pragma unroll
        for (int u = 0; u < 32; ++u) hid[u] += __shfl_xor(hid[u], m, 64);
    }
    float uacc = 0.0f;
#pragma unroll
    for (int u = 0; u < 32; ++u) uacc += tanhf(hid[u] + b1[u]) * w2[u];
    float e = 1.0f / (1.0f + expf(-(uacc + b2v[0])));
    if (lane == 0) {
        energy_ws[token] = e;
        d_out[OUT_E + token] = e;
        if (e > 0.5f) atomicAdd(&d_out[OUT_CNT], 1.0f);
    }
}

// ---------------------------------------------------------------- top-k via bitonic sort
__global__ __launch_bounds__(256)
void topk_kernel(const float* __restrict__ energy, int* __restrict__ idx) {
    __shared__ unsigned long long keys[2048];
    __shared__ unsigned int sel[1024];
    int tid = threadIdx.x, b = blockIdx.x;
    for (int i = tid; i < 2048; i += 256) {
        unsigned int u = __float_as_uint(energy[b * Tz + i]);  // energies > 0
        keys[i] = ((unsigned long long)(~u) << 32) | (unsigned int)i;
    }
    for (int k2 = 2; k2 <= 2048; k2 <<= 1) {
        for (int j = k2 >> 1; j > 0; j >>= 1) {
            __syncthreads();
            for (int i = tid; i < 2048; i += 256) {
                int ixj = i ^ j;
                if (ixj > i) {
                    bool up = ((i & k2) == 0);
                    unsigned long long a = keys[i], c = keys[ixj];
                    if ((a > c) == up) { keys[i] = c; keys[ixj] = a; }
                }
            }
        }
    }
    __syncthreads();
    for (int i = tid; i < 1024; i += 256) sel[i] = (unsigned int)(keys[i] & 0xffffffffu);
    for (int k2 = 2; k2 <= 1024; k2 <<= 1) {
        for (int j = k2 >> 1; j > 0; j >>= 1) {
            __syncthreads();
            for (int i = tid; i < 1024; i += 256) {
                int ixj = i ^ j;
                if (ixj > i) {
                    bool up = ((i & k2) == 0);
                    unsigned int a = sel[i], c = sel[ixj];
                    if ((a > c) == up) { sel[i] = c; sel[ixj] = a; }
                }
            }
        }
    }
    __syncthreads();
    for (int i = tid; i < 1024; i += 256) idx[b * KSEL + i] = (int)sel[i];
}

// ---------------------------------------------------------------- gather + bf16
__global__ void gather_sel(const float* __restrict__ h_rnn, const int* __restrict__ idx,
                           unsigned short* __restrict__ x_sel) {
    int i4 = blockIdx.x * 256 + threadIdx.x;   // MSEL*192 total
    int r = i4 / 192, c4 = (i4 % 192) * 4;
    int b = r >> 10;
    float4 v = *(const float4*)&h_rnn[((size_t)(b << 11) + idx[r]) * Cz + c4];
    ushort4 o;
    o.x = f2bf(v.x); o.y = f2bf(v.y); o.z = f2bf(v.z); o.w = f2bf(v.w);
    *(ushort4*)&x_sel[(size_t)r * Cz + c4] = o;
}

__global__ void scatter_pos(const int* __restrict__ idx, int* __restrict__ pos) {
    int i = blockIdx.x * 256 + threadIdx.x;
    if (i < MSEL) {
        int b = i >> 10;
        pos[(b << 11) + idx[i]] = i & 1023;
    }
}

// ---------------------------------------------------------------- bf16 MFMA GEMM (NT)
template <int EPI>
__global__ __launch_bounds__(256)
void gemm_bf16(const unsigned short* __restrict__ A, const unsigned short* __restrict__ W,
               const float* __restrict__ bias, float* __restrict__ out_f,
               unsigned short* __restrict__ out_b, const float* __restrict__ res,
               int M, int N, int K) {
    __shared__ unsigned short As[128][72];
    __shared__ unsigned short Bs[128][72];
    int tid = threadIdx.x;
    int wid = tid >> 6, lane = tid & 63;
    int quad = lane >> 4, l16 = lane & 15;
    int wm = (wid >> 1) * 64, wn = (wid & 1) * 64;
    int m0 = blockIdx.y * 128, n0 = blockIdx.x * 128;

    floatx4 acc[4][4];
#pragma unroll
    for (int i = 0; i < 4; ++i)
#pragma unroll
        for (int j = 0; j < 4; ++j) acc[i][j] = floatx4{0.f, 0.f, 0.f, 0.f};

    for (int k0 = 0; k0 < K; k0 += 64) {
        __syncthreads();
        for (int f = tid; f < 1024; f += 256) {
            int r = f >> 3, cc = (f & 7) * 8;
            *(uint4*)&As[r][cc] = *(const uint4*)&A[(size_t)(m0 + r) * K + k0 + cc];
            *(uint4*)&Bs[r][cc] = *(const uint4*)&W[(size_t)(n0 + r) * K + k0 + cc];
        }
        __syncthreads();
#pragma unroll
        for (int kh = 0; kh < 2; ++kh) {
            short8 af[4], bf[4];
#pragma unroll
            for (int i = 0; i < 4; ++i)
                af[i] = *(const short8*)&As[wm + i * 16 + l16][kh * 32 + quad * 8];
#pragma unroll
            for (int i = 0; i < 4; ++i)
                bf[i] = *(const short8*)&Bs[wn + i * 16 + l16][kh * 32 + quad * 8];
#pragma unroll
            for (int mi = 0; mi < 4; ++mi)
#pragma unroll
                for (int ni = 0; ni < 4; ++ni)
                    acc[mi][ni] = __builtin_amdgcn_mfma_f32_16x16x32_bf16(
                        af[mi], bf[ni], acc[mi][ni], 0, 0, 0);
        }
    }

#pragma unroll
    for (int mi = 0; mi < 4; ++mi) {
#pragma unroll
        for (int ni = 0; ni < 4; ++ni) {
            int n = n0 + wn + ni * 16 + l16;
            float bv = bias[n];
#pragma unroll
            for (int r = 0; r < 4; ++r) {
                int m = m0 + wm + mi * 16 + quad * 4 + r;
                float val = acc[mi][ni][r] + bv;
                if constexpr (EPI == 0) {
                    out_f[(size_t)m * N + n] = val;
                } else if constexpr (EPI == 1) {
                    int b = m >> 10, kk = m & 1023;
                    int which = n / Cz;
                    int rr = n - which * Cz;
                    int h = rr >> 6, d = rr & 63;
                    out_b[(size_t)which * QKV_STRIDE +
                          (((size_t)(b * Hz + h) * KSEL + kk) << 6) + d] = f2bf(val);
                } else if constexpr (EPI == 2) {
                    out_b[(size_t)m * N + n] = f2bf(gelu_exact(val));
                } else {
                    out_f[(size_t)m * N + n] = val + res[(size_t)m * N + n];
                }
            }
        }
    }
}

// ---------------------------------------------------------------- flash attention
__global__ __launch_bounds__(256)
void flash_attn(const unsigned short* __restrict__ qkvb, unsigned short* __restrict__ y_rows) {
    __shared__ unsigned short Qs[64][88];
    __shared__ unsigned short Ks[64][88];
    __shared__ unsigned short Vt[64][88];
    __shared__ unsigned short Ps[4][16][88];
    int tid = threadIdx.x;
    int wid = tid >> 6, lane = tid & 63;
    int quad = lane >> 4, l16 = lane & 15;
    int wq0 = wid * 16;
    int qt = blockIdx.x, bh = blockIdx.y;
    int q0 = qt * 64;
    const unsigned short* Qg = qkvb + ((size_t)bh * KSEL << 6);
    const unsigned short* Kg = Qg + QKV_STRIDE;
    const unsigned short* Vg = Qg + 2 * QKV_STRIDE;
    int b = bh / Hz, h = bh - b * Hz;

    for (int f = tid; f < 512; f += 256) {
        int r = f >> 3, cc = (f & 7) * 8;
        *(uint4*)&Qs[r][cc] = *(const uint4*)&Qg[(size_t)(q0 + r) * 64 + cc];
    }

    float m_i[4], l_i[4];
    floatx4 oacc[4];
#pragma unroll
    for (int r = 0; r < 4; ++r) { m_i[r] = -3.0e38f; l_i[r] = 0.0f; }
#pragma unroll
    for (int d = 0; d < 4; ++d) oacc[d] = floatx4{0.f, 0.f, 0.f, 0.f};

    for (int jt = 0; jt <= qt; ++jt) {
        int k0 = jt * 64;
        __syncthreads();
        for (int f = tid; f < 512; f += 256) {
            int r = f >> 3, cc = (f & 7) * 8;
            *(uint4*)&Ks[r][cc] = *(const uint4*)&Kg[(size_t)(k0 + r) * 64 + cc];
            uint4 v = *(const uint4*)&Vg[(size_t)(k0 + r) * 64 + cc];
            const unsigned short* pv = (const unsigned short*)&v;
#pragma unroll
            for (int e = 0; e < 8; ++e) Vt[cc + e][r] = pv[e];
        }
        __syncthreads();

        floatx4 sacc[4];
#pragma unroll
        for (int ni = 0; ni < 4; ++ni) sacc[ni] = floatx4{0.f, 0.f, 0.f, 0.f};
#pragma unroll
        for (int kh = 0; kh < 2; ++kh) {
            short8 aq = *(const short8*)&Qs[wq0 + l16][kh * 32 + quad * 8];
#pragma unroll
            for (int ni = 0; ni < 4; ++ni) {
                short8 bk = *(const short8*)&Ks[ni * 16 + l16][kh * 32 + quad * 8];
                sacc[ni] = __builtin_amdgcn_mfma_f32_16x16x32_bf16(aq, bk, sacc[ni], 0, 0, 0);
            }
        }
#pragma unroll
        for (int ni = 0; ni < 4; ++ni) {
            int kg = k0 + ni * 16 + l16;
#pragma unroll
            for (int r = 0; r < 4; ++r) {
                int qg = q0 + wq0 + quad * 4 + r;
                float s = sacc[ni][r] * 0.125f;
                sacc[ni][r] = (kg > qg) ? -1.0e30f : s;
            }
        }
        float alpha[4];
#pragma unroll
        for (int r = 0; r < 4; ++r) {
            float mx = sacc[0][r];
#pragma unroll
            for (int ni = 1; ni < 4; ++ni) mx = fmaxf(mx, sacc[ni][r]);
#pragma unroll
            for (int m = 1; m <= 8; m <<= 1) mx = fmaxf(mx, __shfl_xor(mx, m, 64));
            float mn = fmaxf(m_i[r], mx);
            alpha[r] = expf(m_i[r] - mn);
            float rs = 0.0f;
#pragma unroll
            for (int ni = 0; ni < 4; ++ni) {
                float p = expf(sacc[ni][r] - mn);
                sacc[ni][r] = p;
                rs += p;
            }
#pragma unroll
            for (int m = 1; m <= 8; m <<= 1) rs += __shfl_xor(rs, m, 64);
            m_i[r] = mn;
            l_i[r] = l_i[r] * alpha[r] + rs;
        }
#pragma unroll
        for (int ni = 0; ni < 4; ++ni)
#pragma unroll
            for (int r = 0; r < 4; ++r)
                Ps[wid][quad * 4 + r][ni * 16 + l16] = f2bf(sacc[ni][r]);
#pragma unroll
        for (int d = 0; d < 4; ++d)
#pragma unroll
            for (int r = 0; r < 4; ++r) oacc[d][r] *= alpha[r];
#pragma unroll
        for (int kh = 0; kh < 2; ++kh) {
            short8 ap = *(const short8*)&Ps[wid][l16][kh * 32 + quad * 8];
#pragma unroll
            for (int d = 0; d < 4; ++d) {
                short8 bv = *(const short8*)&Vt[d * 16 + l16][kh * 32 + quad * 8];
                oacc[d] = __builtin_amdgcn_mfma_f32_16x16x32_bf16(ap, bv, oacc[d], 0, 0, 0);
            }
        }
    }
#pragma unroll
    for (int r = 0; r < 4; ++r) {
        float inv = 1.0f / l_i[r];
        size_t row = (size_t)b * KSEL + q0 + wq0 + quad * 4 + r;
#pragma unroll
        for (int d = 0; d < 4; ++d)
            y_rows[row * Cz + h * 64 + d * 16 + l16] = f2bf(oacc[d][r] * inv);
    }
}

// ---------------------------------------------------------------- scatter + LayerNorm (in-place on h)
__global__ __launch_bounds__(256)
void ln_fuse(float* h, const float* __restrict__ proj_out,
             const int* __restrict__ pos, const float* __restrict__ energy_ws,
             const float* __restrict__ ln_g, const float* __restrict__ ln_b,
             unsigned short* __restrict__ h_ln_bf) {
    int wid = threadIdx.x >> 6, lane = threadIdx.x & 63;
    int token = blockIdx.x * 4 + wid;
    int b = token >> 11;
    float* hrow = h + (size_t)token * Cz;
    int p = pos[token];
    float gsc = (p >= 0) ? energy_ws[token] : 0.0f;
    const float* prow = proj_out + ((size_t)(b << 10) + (p >= 0 ? p : 0)) * Cz;
    float x[12], s1 = 0.0f, s2 = 0.0f;
#pragma unroll
    for (int j = 0; j < 12; ++j) {
        int c = lane + 64 * j;
        float v = hrow[c] + gsc * prow[c];
        x[j] = v;
        s1 += v;
        s2 += v * v;
    }
#pragma unroll
    for (int m = 1; m <= 32; m <<= 1) {
        s1 += __shfl_xor(s1, m, 64);
        s2 += __shfl_xor(s2, m, 64);
    }
    float mu = s1 * (1.0f / 768.0f);
    float var = s2 * (1.0f / 768.0f) - mu * mu;
    var = fmaxf(var, 0.0f);
    float rs = 1.0f / sqrtf(var + 1e-5f);
#pragma unroll
    for (int j = 0; j < 12; ++j) {
        int c = lane + 64 * j;
        float y = (x[j] - mu) * rs * ln_g[c] + ln_b[c];
        hrow[c] = y;
        h_ln_bf[(size_t)token * Cz + c] = f2bf(y);
    }
}

// ---------------------------------------------------------------- launch
extern "C" void kernel_launch(void* const* d_in, const int* in_sizes, int n_in,
                              void* d_out, int out_size, void* d_ws, size_t ws_size,
                              hipStream_t stream) {
    (void)in_sizes; (void)n_in; (void)out_size; (void)ws_size;
    const float* x      = (const float*)d_in[0];
    const float* W_ih   = (const float*)d_in[1];
    const float* W_hh   = (const float*)d_in[2];
    const float* b_ih   = (const float*)d_in[3];
    const float* b_hh   = (const float*)d_in[4];
    const float* gw1    = (const float*)d_in[5];
    const float* gb1    = (const float*)d_in[6];
    const float* gw2    = (const float*)d_in[7];
    const float* gb2    = (const float*)d_in[8];
    const float* qkv_w  = (const float*)d_in[9];
    const float* qkv_b  = (const float*)d_in[10];
    const float* proj_w = (const float*)d_in[11];
    const float* proj_b = (const float*)d_in[12];
    const float* ln_g   = (const float*)d_in[13];
    const float* ln_b   = (const float*)d_in[14];
    const float* ffn_w1 = (const float*)d_in[15];
    const float* ffn_b1 = (const float*)d_in[16];
    const float* ffn_w2 = (const float*)d_in[17];
    const float* ffn_b2 = (const float*)d_in[18];
    float* out = (float*)d_out;

    // -------- workspace layout (lifetime-aliased; peak ~215.7 MB) --------
    char* ws = (char*)d_ws;
    float* xi               = (float*)ws;
    unsigned short* x_sel   = (unsigned short*)ws;
    unsigned short* qkvb    = (unsigned short*)(ws + 13631488);
    unsigned short* y_rows  = (unsigned short*)ws;
    float* proj_out         = (float*)(ws + 52428800);
    unsigned short* h_ln_bf = (unsigned short*)ws;
    unsigned short* a1      = (unsigned short*)(ws + 25165824);
    float* h_rnn     = (float*)(ws + 150994944);
    float* energy_ws = (float*)(ws + 201326592);
    int*   idx       = (int*)(ws + 201392128);
    int*   pos       = (int*)(ws + 201424896);
    unsigned short* qkv_w_b  = (unsigned short*)(ws + 201490432);
    unsigned short* proj_w_b = (unsigned short*)(ws + 205029376);
    unsigned short* w1_b     = (unsigned short*)(ws + 206209024);
    unsigned short* w2_b     = (unsigned short*)(ws + 210927616);
    int*   cnt       = (int*)(ws + 215646208);   // 8*2048 ints = 64 KB
    // end: 215,711,744 B

    init_ws<<<64, 256, 0, stream>>>(pos, cnt, out);
    cvt_bf16<<<2048, 256, 0, stream>>>(qkv_w, qkv_w_b, G3 * Cz);
    cvt_bf16<<<2048, 256, 0, stream>>>(proj_w, proj_w_b, Cz * Cz);
    cvt_bf16<<<2048, 256, 0, stream>>>(ffn_w1, w1_b, DFF * Cz);
    cvt_bf16<<<2048, 256, 0, stream>>>(ffn_w2, w2_b, Cz * DFF);

    gemm_f32_nt<<<dim3(G3 / 128, MTOK / 128), 256, 0, stream>>>(x, W_ih, b_ih, xi,
                                                                MTOK, G3, Cz);
    gru_scan<<<GRU_WGS, 256, 0, stream>>>(xi, W_hh, b_hh, h_rnn, cnt);

    gate_energy<<<MTOK / 4, 256, 0, stream>>>(h_rnn, gw1, gb1, gw2, gb2, energy_ws, out);
    topk_kernel<<<Bz, 256, 0, stream>>>(energy_ws, idx);
    scatter_pos<<<MSEL / 256, 256, 0, stream>>>(idx, pos);
    gather_sel<<<MSEL * 192 / 256, 256, 0, stream>>>(h_rnn, idx, x_sel);

    gemm_bf16<1><<<dim3(G3 / 128, MSEL / 128), 256, 0, stream>>>(
        x_sel, qkv_w_b, qkv_b, nullptr, qkvb, nullptr, MSEL, G3, Cz);
    flash_attn<<<dim3(16, Bz * Hz), 256, 0, stream>>>(qkvb, y_rows);
    gemm_bf16<0><<<dim3(Cz / 128, MSEL / 128), 256, 0, stream>>>(
        y_rows, proj_w_b, proj_b, proj_out, nullptr, nullptr, MSEL, Cz, Cz);
    ln_fuse<<<MTOK / 4, 256, 0, stream>>>(h_rnn, proj_out, pos, energy_ws, ln_g, ln_b,
                                          h_ln_bf);
    gemm_bf16<2><<<dim3(DFF / 128, MTOK / 128), 256, 0, stream>>>(
        h_ln_bf, w1_b, ffn_b1, nullptr, a1, nullptr, MTOK, DFF, Cz);
    gemm_bf16<3><<<dim3(Cz / 128, MTOK / 128), 256, 0, stream>>>(
        a1, w2_b, ffn_b2, out, nullptr, h_rnn, MTOK, Cz, DFF);
}

// Round 6
// 14044.479 us; speedup vs baseline: 8.4009x; 5.3393x over previous
//
#include <hip/hip_runtime.h>
#include <cstdint>
#include <cstddef>

#define DI static __device__ __forceinline__

typedef __attribute__((ext_vector_type(8))) short short8;
typedef __attribute__((ext_vector_type(4))) float floatx4;

constexpr int Bz = 8, Tz = 2048, Cz = 768, Hz = 12;
constexpr int G3 = 2304;          // 3C
constexpr int KSEL = 1024;        // T/2 selected tokens
constexpr int DFF = 3072;
constexpr int MTOK = Bz * Tz;     // 16384
constexpr int MSEL = Bz * KSEL;   // 8192
constexpr size_t OUT_E   = (size_t)MTOK * Cz;    // 12582912
constexpr size_t OUT_CNT = OUT_E + (size_t)MTOK; // 12599296
constexpr size_t QKV_STRIDE = (size_t)Bz * Hz * KSEL * 64; // 6291456 elements
constexpr int WPG = 48;           // workgroups per batch-group (16 cols each)
constexpr int GRU_WGS = Bz * WPG; // 384  (<= 2 blocks/CU * 256 CUs, all resident)

DI unsigned short f2bf(float f) {
    unsigned int u = __float_as_uint(f);
    unsigned int r = u + 0x7fffu + ((u >> 16) & 1u);
    return (unsigned short)(r >> 16);
}
DI float gelu_exact(float x) {
    return 0.5f * x * (1.0f + erff(x * 0.70710678118654752440f));
}

// ---------------------------------------------------------------- init
__global__ void init_ws(int* pos, int* cnt, float* d_out) {
    int i = blockIdx.x * 256 + threadIdx.x;
    if (i < MTOK) pos[i] = -1;
    if (i < Bz * Tz) cnt[i] = 0;
    if (i == 0) d_out[OUT_CNT] = 0.0f;
}

// ---------------------------------------------------------------- f32 -> bf16
__global__ void cvt_bf16(const float* __restrict__ src, unsigned short* __restrict__ dst, int n) {
    int i = blockIdx.x * 256 + threadIdx.x;
    int stride = gridDim.x * 256;
    for (; i < n; i += stride) dst[i] = f2bf(src[i]);
}

// ---------------------------------------------------------------- f32 NT GEMM (xi)
__global__ __launch_bounds__(256)
void gemm_f32_nt(const float* __restrict__ A, const float* __restrict__ W,
                 const float* __restrict__ bias, float* __restrict__ out,
                 int M, int N, int K) {
    __shared__ float As[16][132];
    __shared__ float Bs[16][132];
    int tid = threadIdx.x;
    int tx = tid & 15, ty = tid >> 4;
    int m0 = blockIdx.y * 128, n0 = blockIdx.x * 128;
    float acc[8][8];
#pragma unroll
    for (int i = 0; i < 8; ++i)
#pragma unroll
        for (int j = 0; j < 8; ++j) acc[i][j] = 0.0f;

    for (int k0 = 0; k0 < K; k0 += 16) {
        __syncthreads();
        for (int f = tid; f < 512; f += 256) {
            int r = f >> 2, c4 = (f & 3) << 2;
            float4 v = *(const float4*)&A[(size_t)(m0 + r) * K + k0 + c4];
            As[c4 + 0][r] = v.x; As[c4 + 1][r] = v.y; As[c4 + 2][r] = v.z; As[c4 + 3][r] = v.w;
            float4 w = *(const float4*)&W[(size_t)(n0 + r) * K + k0 + c4];
            Bs[c4 + 0][r] = w.x; Bs[c4 + 1][r] = w.y; Bs[c4 + 2][r] = w.z; Bs[c4 + 3][r] = w.w;
        }
        __syncthreads();
#pragma unroll 4
        for (int k = 0; k < 16; ++k) {
            float a[8], b[8];
            *(float4*)&a[0] = *(float4*)&As[k][ty * 8];
            *(float4*)&a[4] = *(float4*)&As[k][ty * 8 + 4];
            *(float4*)&b[0] = *(float4*)&Bs[k][tx * 8];
            *(float4*)&b[4] = *(float4*)&Bs[k][tx * 8 + 4];
#pragma unroll
            for (int i = 0; i < 8; ++i)
#pragma unroll
                for (int j = 0; j < 8; ++j) acc[i][j] += a[i] * b[j];
        }
    }
#pragma unroll
    for (int i = 0; i < 8; ++i) {
        int m = m0 + ty * 8 + i;
        int n = n0 + tx * 8;
        float4 o0{acc[i][0] + bias[n + 0], acc[i][1] + bias[n + 1],
                  acc[i][2] + bias[n + 2], acc[i][3] + bias[n + 3]};
        float4 o1{acc[i][4] + bias[n + 4], acc[i][5] + bias[n + 5],
                  acc[i][6] + bias[n + 6], acc[i][7] + bias[n + 7]};
        *(float4*)&out[(size_t)m * N + n] = o0;
        *(float4*)&out[(size_t)m * N + n + 4] = o1;
    }
}

// ---------------------------------------------------------------- GRU scan
// Fence-free cross-WG exchange, race-fixed vs R5:
//  * h(t) is PUBLISHED with a system-scope atomic exchange (far-atomic RMW,
//    performed AT the L3 coherence point). The returned old value is consumed
//    (stored to a dead LDS pad slot), forcing s_waitcnt on the L3 response —
//    so when the wave passes __syncthreads, the data is PROVEN resident at L3.
//    (R5's plain write-through store could retire vmcnt while still in flight
//    to L3, letting the counter bump overtake the data -> rare stale reads.)
//  * Counter: relaxed system-scope fetch_add + relaxed poll.
//  * h(t-1) staged with cache-bypassing system-scope loads (read L3 direct).
//  * No __threadfence anywhere -> zero buffer_wbl2/buffer_inv per step.
__global__ __launch_bounds__(256, 2)
void gru_scan(const float* __restrict__ xi, const float* __restrict__ W_hh,
              const float* __restrict__ b_hh, float* __restrict__ h_rnn,
              int* __restrict__ cnt) {
    __shared__ float hs[768];        // h(t-1) for this batch
    __shared__ float part[48][17];   // k-chunk partials; column 16 is a pad
    __shared__ float hh[48];
    __shared__ float bhh[48];
    int tid = threadIdx.x;
    int g = blockIdx.x / WPG;        // batch
    int w = blockIdx.x % WPG;        // col group
    int c0 = w * 16;
    int rowgrp = tid & 15;           // owns local rows lr0..lr0+2
    int kc = tid >> 4;               // k chunk (48 wide), 0..15
    int lr0 = rowgrp * 3;

    // W_hh slice -> registers. local row lr: gate=lr>>4, col=lr&15.
    float4 Wreg[3][12];
#pragma unroll
    for (int i = 0; i < 3; ++i) {
        int lr = lr0 + i;
        size_t grow = (size_t)((lr >> 4) * Cz + c0 + (lr & 15));
        const float4* src = (const float4*)&W_hh[grow * Cz + kc * 48];
#pragma unroll
        for (int q = 0; q < 12; ++q) Wreg[i][q] = src[q];
    }
    if (tid < 48) bhh[tid] = b_hh[(tid >> 4) * Cz + c0 + (tid & 15)];
    int* mycnt = cnt + g * Tz;
    __syncthreads();

    for (int t = 0; t < Tz; ++t) {
        // prefetch xi for this step (read-only, normal cached loads)
        float xr = 0.f, xz = 0.f, xn = 0.f;
        if (tid < 16) {
            const float* xrow = xi + ((size_t)g * Tz + t) * G3 + c0 + tid;
            xr = xrow[0]; xz = xrow[Cz]; xn = xrow[2 * Cz];
        }
        // stage h(t-1) into LDS via cache-bypassing loads (reads L3)
        if (t == 0) {
            if (tid < 192) *(float4*)&hs[tid * 4] = float4{0.f, 0.f, 0.f, 0.f};
        } else {
            const float* hprevrow = h_rnn + ((size_t)g * Tz + (t - 1)) * Cz;
#pragma unroll
            for (int i = tid; i < 768; i += 256)
                hs[i] = __hip_atomic_load(&hprevrow[i], __ATOMIC_RELAXED,
                                          __HIP_MEMORY_SCOPE_SYSTEM);
        }
        __syncthreads();

        // partial matvec: 3 rows x 48 k per thread
        float acc0 = 0.f, acc1 = 0.f, acc2 = 0.f;
        const float4* hv = (const float4*)&hs[kc * 48];
#pragma unroll
        for (int q = 0; q < 12; ++q) {
            float4 h4 = hv[q];
            acc0 += Wreg[0][q].x * h4.x + Wreg[0][q].y * h4.y +
                    Wreg[0][q].z * h4.z + Wreg[0][q].w * h4.w;
            acc1 += Wreg[1][q].x * h4.x + Wreg[1][q].y * h4.y +
                    Wreg[1][q].z * h4.z + Wreg[1][q].w * h4.w;
            acc2 += Wreg[2][q].x * h4.x + Wreg[2][q].y * h4.y +
                    Wreg[2][q].z * h4.z + Wreg[2][q].w * h4.w;
        }
        part[lr0 + 0][kc] = acc0;
        part[lr0 + 1][kc] = acc1;
        part[lr0 + 2][kc] = acc2;
        __syncthreads();
        if (tid < 48) {
            float s = 0.f;
#pragma unroll
            for (int q = 0; q < 16; ++q) s += part[tid][q];
            hh[tid] = s + bhh[tid];
        }
        __syncthreads();
        if (tid < 16) {
            float hr = hh[tid], hz = hh[16 + tid], hn = hh[32 + tid];
            float hp = hs[c0 + tid];
            float r = 1.0f / (1.0f + expf(-(xr + hr)));
            float z = 1.0f / (1.0f + expf(-(xz + hz)));
            float n = tanhf(xn + r * hn);
            float hnew = (1.0f - z) * n + z * hp;
            // publish via far-atomic exchange: performed AT the L3 coherence
            // point; consuming the returned value forces the wave to wait for
            // the L3 ack -> data is globally visible before we pass the
            // barrier below.
            float old = __hip_atomic_exchange(
                &h_rnn[((size_t)g * Tz + t) * Cz + c0 + tid], hnew,
                __ATOMIC_RELAXED, __HIP_MEMORY_SCOPE_SYSTEM);
            part[0][16] = old;   // dead pad slot, never read; keeps the wait
        }
        __syncthreads();   // wave 0 drains vmcnt(0) before s_barrier
        if (tid == 0) {
            __hip_atomic_fetch_add(mycnt + t, 1, __ATOMIC_RELAXED,
                                   __HIP_MEMORY_SCOPE_SYSTEM);
            while (__hip_atomic_load(mycnt + t, __ATOMIC_RELAXED,
                                     __HIP_MEMORY_SCOPE_SYSTEM) < WPG)
                __builtin_amdgcn_s_sleep(1);
        }
        __syncthreads();
    }
}

// ---------------------------------------------------------------- gate MLP / energy
__global__ __launch_bounds__(256)
void gate_energy(const float* __restrict__ h_rnn, const float* __restrict__ w1,
                 const float* __restrict__ b1, const float* __restrict__ w2,
                 const float* __restrict__ b2v, float* __restrict__ energy_ws,
                 float* __restrict__ d_out) {
    int wid = threadIdx.x >> 6, lane = threadIdx.x & 63;
    int token = blockIdx.x * 4 + wid;
    const float* hrow = h_rnn + (size_t)token * Cz;
    float hid[32];
#pragma unroll
    for (int u = 0; u < 32; ++u) hid[u] = 0.0f;
#pragma unroll
    for (int j = 0; j < 12; ++j) {
        int c = lane + 64 * j;
        float x = hrow[c];
#pragma unroll
        for (int u = 0; u < 32; ++u) hid[u] += x * w1[u * Cz + c];
    }
#pragma unroll
    for (int m = 1; m <= 32; m <<= 1) {
#pragma unroll
        for (int u = 0; u < 32; ++u) hid[u] += __shfl_xor(hid[u], m, 64);
    }
    float uacc = 0.0f;
#pragma unroll
    for (int u = 0; u < 32; ++u) uacc += tanhf(hid[u] + b1[u]) * w2[u];
    float e = 1.0f / (1.0f + expf(-(uacc + b2v[0])));
    if (lane == 0) {
        energy_ws[token] = e;
        d_out[OUT_E + token] = e;
        if (e > 0.5f) atomicAdd(&d_out[OUT_CNT], 1.0f);
    }
}

// ---------------------------------------------------------------- top-k via bitonic sort
__global__ __launch_bounds__(256)
void topk_kernel(const float* __restrict__ energy, int* __restrict__ idx) {
    __shared__ unsigned long long keys[2048];
    __shared__ unsigned int sel[1024];
    int tid = threadIdx.x, b = blockIdx.x;
    for (int i = tid; i < 2048; i += 256) {
        unsigned int u = __float_as_uint(energy[b * Tz + i]);  // energies > 0
        keys[i] = ((unsigned long long)(~u) << 32) | (unsigned int)i;
    }
    for (int k2 = 2; k2 <= 2048; k2 <<= 1) {
        for (int j = k2 >> 1; j > 0; j >>= 1) {
            __syncthreads();
            for (int i = tid; i < 2048; i += 256) {
                int ixj = i ^ j;
                if (ixj > i) {
                    bool up = ((i & k2) == 0);
                    unsigned long long a = keys[i], c = keys[ixj];
                    if ((a > c) == up) { keys[i] = c; keys[ixj] = a; }
                }
            }
        }
    }
    __syncthreads();
    for (int i = tid; i < 1024; i += 256) sel[i] = (unsigned int)(keys[i] & 0xffffffffu);
    for (int k2 = 2; k2 <= 1024; k2 <<= 1) {
        for (int j = k2 >> 1; j > 0; j >>= 1) {
            __syncthreads();
            for (int i = tid; i < 1024; i += 256) {
                int ixj = i ^ j;
                if (ixj > i) {
                    bool up = ((i & k2) == 0);
                    unsigned int a = sel[i], c = sel[ixj];
                    if ((a > c) == up) { sel[i] = c; sel[ixj] = a; }
                }
            }
        }
    }
    __syncthreads();
    for (int i = tid; i < 1024; i += 256) idx[b * KSEL + i] = (int)sel[i];
}

// ---------------------------------------------------------------- gather + bf16
__global__ void gather_sel(const float* __restrict__ h_rnn, const int* __restrict__ idx,
                           unsigned short* __restrict__ x_sel) {
    int i4 = blockIdx.x * 256 + threadIdx.x;   // MSEL*192 total
    int r = i4 / 192, c4 = (i4 % 192) * 4;
    int b = r >> 10;
    float4 v = *(const float4*)&h_rnn[((size_t)(b << 11) + idx[r]) * Cz + c4];
    ushort4 o;
    o.x = f2bf(v.x); o.y = f2bf(v.y); o.z = f2bf(v.z); o.w = f2bf(v.w);
    *(ushort4*)&x_sel[(size_t)r * Cz + c4] = o;
}

__global__ void scatter_pos(const int* __restrict__ idx, int* __restrict__ pos) {
    int i = blockIdx.x * 256 + threadIdx.x;
    if (i < MSEL) {
        int b = i >> 10;
        pos[(b << 11) + idx[i]] = i & 1023;
    }
}

// ---------------------------------------------------------------- bf16 MFMA GEMM (NT)
template <int EPI>
__global__ __launch_bounds__(256)
void gemm_bf16(const unsigned short* __restrict__ A, const unsigned short* __restrict__ W,
               const float* __restrict__ bias, float* __restrict__ out_f,
               unsigned short* __restrict__ out_b, const float* __restrict__ res,
               int M, int N, int K) {
    __shared__ unsigned short As[128][72];
    __shared__ unsigned short Bs[128][72];
    int tid = threadIdx.x;
    int wid = tid >> 6, lane = tid & 63;
    int quad = lane >> 4, l16 = lane & 15;
    int wm = (wid >> 1) * 64, wn = (wid & 1) * 64;
    int m0 = blockIdx.y * 128, n0 = blockIdx.x * 128;

    floatx4 acc[4][4];
#pragma unroll
    for (int i = 0; i < 4; ++i)
#pragma unroll
        for (int j = 0; j < 4; ++j) acc[i][j] = floatx4{0.f, 0.f, 0.f, 0.f};

    for (int k0 = 0; k0 < K; k0 += 64) {
        __syncthreads();
        for (int f = tid; f < 1024; f += 256) {
            int r = f >> 3, cc = (f & 7) * 8;
            *(uint4*)&As[r][cc] = *(const uint4*)&A[(size_t)(m0 + r) * K + k0 + cc];
            *(uint4*)&Bs[r][cc] = *(const uint4*)&W[(size_t)(n0 + r) * K + k0 + cc];
        }
        __syncthreads();
#pragma unroll
        for (int kh = 0; kh < 2; ++kh) {
            short8 af[4], bf[4];
#pragma unroll
            for (int i = 0; i < 4; ++i)
                af[i] = *(const short8*)&As[wm + i * 16 + l16][kh * 32 + quad * 8];
#pragma unroll
            for (int i = 0; i < 4; ++i)
                bf[i] = *(const short8*)&Bs[wn + i * 16 + l16][kh * 32 + quad * 8];
#pragma unroll
            for (int mi = 0; mi < 4; ++mi)
#pragma unroll
                for (int ni = 0; ni < 4; ++ni)
                    acc[mi][ni] = __builtin_amdgcn_mfma_f32_16x16x32_bf16(
                        af[mi], bf[ni], acc[mi][ni], 0, 0, 0);
        }
    }

#pragma unroll
    for (int mi = 0; mi < 4; ++mi) {
#pragma unroll
        for (int ni = 0; ni < 4; ++ni) {
            int n = n0 + wn + ni * 16 + l16;
            float bv = bias[n];
#pragma unroll
            for (int r = 0; r < 4; ++r) {
                int m = m0 + wm + mi * 16 + quad * 4 + r;
                float val = acc[mi][ni][r] + bv;
                if constexpr (EPI == 0) {
                    out_f[(size_t)m * N + n] = val;
                } else if constexpr (EPI == 1) {
                    int b = m >> 10, kk = m & 1023;
                    int which = n / Cz;
                    int rr = n - which * Cz;
                    int h = rr >> 6, d = rr & 63;
                    out_b[(size_t)which * QKV_STRIDE +
                          (((size_t)(b * Hz + h) * KSEL + kk) << 6) + d] = f2bf(val);
                } else if constexpr (EPI == 2) {
                    out_b[(size_t)m * N + n] = f2bf(gelu_exact(val));
                } else {
                    out_f[(size_t)m * N + n] = val + res[(size_t)m * N + n];
                }
            }
        }
    }
}

// ---------------------------------------------------------------- flash attention
__global__ __launch_bounds__(256)
void flash_attn(const unsigned short* __restrict__ qkvb, unsigned short* __restrict__ y_rows) {
    __shared__ unsigned short Qs[64][88];
    __shared__ unsigned short Ks[64][88];
    __shared__ unsigned short Vt[64][88];
    __shared__ unsigned short Ps[4][16][88];
    int tid = threadIdx.x;
    int wid = tid >> 6, lane = tid & 63;
    int quad = lane >> 4, l16 = lane & 15;
    int wq0 = wid * 16;
    int qt = blockIdx.x, bh = blockIdx.y;
    int q0 = qt * 64;
    const unsigned short* Qg = qkvb + ((size_t)bh * KSEL << 6);
    const unsigned short* Kg = Qg + QKV_STRIDE;
    const unsigned short* Vg = Qg + 2 * QKV_STRIDE;
    int b = bh / Hz, h = bh - b * Hz;

    for (int f = tid; f < 512; f += 256) {
        int r = f >> 3, cc = (f & 7) * 8;
        *(uint4*)&Qs[r][cc] = *(const uint4*)&Qg[(size_t)(q0 + r) * 64 + cc];
    }

    float m_i[4], l_i[4];
    floatx4 oacc[4];
#pragma unroll
    for (int r = 0; r < 4; ++r) { m_i[r] = -3.0e38f; l_i[r] = 0.0f; }
#pragma unroll
    for (int d = 0; d < 4; ++d) oacc[d] = floatx4{0.f, 0.f, 0.f, 0.f};

    for (int jt = 0; jt <= qt; ++jt) {
        int k0 = jt * 64;
        __syncthreads();
        for (int f = tid; f < 512; f += 256) {
            int r = f >> 3, cc = (f & 7) * 8;
            *(uint4*)&Ks[r][cc] = *(const uint4*)&Kg[(size_t)(k0 + r) * 64 + cc];
            uint4 v = *(const uint4*)&Vg[(size_t)(k0 + r) * 64 + cc];
            const unsigned short* pv = (const unsigned short*)&v;
#pragma unroll
            for (int e = 0; e < 8; ++e) Vt[cc + e][r] = pv[e];
        }
        __syncthreads();

        floatx4 sacc[4];
#pragma unroll
        for (int ni = 0; ni < 4; ++ni) sacc[ni] = floatx4{0.f, 0.f, 0.f, 0.f};
#pragma unroll
        for (int kh = 0; kh < 2; ++kh) {
            short8 aq = *(const short8*)&Qs[wq0 + l16][kh * 32 + quad * 8];
#pragma unroll
            for (int ni = 0; ni < 4; ++ni) {
                short8 bk = *(const short8*)&Ks[ni * 16 + l16][kh * 32 + quad * 8];
                sacc[ni] = __builtin_amdgcn_mfma_f32_16x16x32_bf16(aq, bk, sacc[ni], 0, 0, 0);
            }
        }
#pragma unroll
        for (int ni = 0; ni < 4; ++ni) {
            int kg = k0 + ni * 16 + l16;
#pragma unroll
            for (int r = 0; r < 4; ++r) {
                int qg = q0 + wq0 + quad * 4 + r;
                float s = sacc[ni][r] * 0.125f;
                sacc[ni][r] = (kg > qg) ? -1.0e30f : s;
            }
        }
        float alpha[4];
#pragma unroll
        for (int r = 0; r < 4; ++r) {
            float mx = sacc[0][r];
#pragma unroll
            for (int ni = 1; ni < 4; ++ni) mx = fmaxf(mx, sacc[ni][r]);
#pragma unroll
            for (int m = 1; m <= 8; m <<= 1) mx = fmaxf(mx, __shfl_xor(mx, m, 64));
            float mn = fmaxf(m_i[r], mx);
            alpha[r] = expf(m_i[r] - mn);
            float rs = 0.0f;
#pragma unroll
            for (int ni = 0; ni < 4; ++ni) {
                float p = expf(sacc[ni][r] - mn);
                sacc[ni][r] = p;
                rs += p;
            }
#pragma unroll
            for (int m = 1; m <= 8; m <<= 1) rs += __shfl_xor(rs, m, 64);
            m_i[r] = mn;
            l_i[r] = l_i[r] * alpha[r] + rs;
        }
#pragma unroll
        for (int ni = 0; ni < 4; ++ni)
#pragma unroll
            for (int r = 0; r < 4; ++r)
                Ps[wid][quad * 4 + r][ni * 16 + l16] = f2bf(sacc[ni][r]);
#pragma unroll
        for (int d = 0; d < 4; ++d)
#pragma unroll
            for (int r = 0; r < 4; ++r) oacc[d][r] *= alpha[r];
#pragma unroll
        for (int kh = 0; kh < 2; ++kh) {
            short8 ap = *(const short8*)&Ps[wid][l16][kh * 32 + quad * 8];
#pragma unroll
            for (int d = 0; d < 4; ++d) {
                short8 bv = *(const short8*)&Vt[d * 16 + l16][kh * 32 + quad * 8];
                oacc[d] = __builtin_amdgcn_mfma_f32_16x16x32_bf16(ap, bv, oacc[d], 0, 0, 0);
            }
        }
    }
#pragma unroll
    for (int r = 0; r < 4; ++r) {
        float inv = 1.0f / l_i[r];
        size_t row = (size_t)b * KSEL + q0 + wq0 + quad * 4 + r;
#pragma unroll
        for (int d = 0; d < 4; ++d)
            y_rows[row * Cz + h * 64 + d * 16 + l16] = f2bf(oacc[d][r] * inv);
    }
}

// ---------------------------------------------------------------- scatter + LayerNorm (in-place on h)
__global__ __launch_bounds__(256)
void ln_fuse(float* h, const float* __restrict__ proj_out,
             const int* __restrict__ pos, const float* __restrict__ energy_ws,
             const float* __restrict__ ln_g, const float* __restrict__ ln_b,
             unsigned short* __restrict__ h_ln_bf) {
    int wid = threadIdx.x >> 6, lane = threadIdx.x & 63;
    int token = blockIdx.x * 4 + wid;
    int b = token >> 11;
    float* hrow = h + (size_t)token * Cz;
    int p = pos[token];
    float gsc = (p >= 0) ? energy_ws[token] : 0.0f;
    const float* prow = proj_out + ((size_t)(b << 10) + (p >= 0 ? p : 0)) * Cz;
    float x[12], s1 = 0.0f, s2 = 0.0f;
#pragma unroll
    for (int j = 0; j < 12; ++j) {
        int c = lane + 64 * j;
        float v = hrow[c] + gsc * prow[c];
        x[j] = v;
        s1 += v;
        s2 += v * v;
    }
#pragma unroll
    for (int m = 1; m <= 32; m <<= 1) {
        s1 += __shfl_xor(s1, m, 64);
        s2 += __shfl_xor(s2, m, 64);
    }
    float mu = s1 * (1.0f / 768.0f);
    float var = s2 * (1.0f / 768.0f) - mu * mu;
    var = fmaxf(var, 0.0f);
    float rs = 1.0f / sqrtf(var + 1e-5f);
#pragma unroll
    for (int j = 0; j < 12; ++j) {
        int c = lane + 64 * j;
        float y = (x[j] - mu) * rs * ln_g[c] + ln_b[c];
        hrow[c] = y;
        h_ln_bf[(size_t)token * Cz + c] = f2bf(y);
    }
}

// ---------------------------------------------------------------- launch
extern "C" void kernel_launch(void* const* d_in, const int* in_sizes, int n_in,
                              void* d_out, int out_size, void* d_ws, size_t ws_size,
                              hipStream_t stream) {
    (void)in_sizes; (void)n_in; (void)out_size; (void)ws_size;
    const float* x      = (const float*)d_in[0];
    const float* W_ih   = (const float*)d_in[1];
    const float* W_hh   = (const float*)d_in[2];
    const float* b_ih   = (const float*)d_in[3];
    const float* b_hh   = (const float*)d_in[4];
    const float* gw1    = (const float*)d_in[5];
    const float* gb1    = (const float*)d_in[6];
    const float* gw2    = (const float*)d_in[7];
    const float* gb2    = (const float*)d_in[8];
    const float* qkv_w  = (const float*)d_in[9];
    const float* qkv_b  = (const float*)d_in[10];
    const float* proj_w = (const float*)d_in[11];
    const float* proj_b = (const float*)d_in[12];
    const float* ln_g   = (const float*)d_in[13];
    const float* ln_b   = (const float*)d_in[14];
    const float* ffn_w1 = (const float*)d_in[15];
    const float* ffn_b1 = (const float*)d_in[16];
    const float* ffn_w2 = (const float*)d_in[17];
    const float* ffn_b2 = (const float*)d_in[18];
    float* out = (float*)d_out;

    // -------- workspace layout (lifetime-aliased; peak ~215.7 MB) --------
    char* ws = (char*)d_ws;
    float* xi               = (float*)ws;
    unsigned short* x_sel   = (unsigned short*)ws;
    unsigned short* qkvb    = (unsigned short*)(ws + 13631488);
    unsigned short* y_rows  = (unsigned short*)ws;
    float* proj_out         = (float*)(ws + 52428800);
    unsigned short* h_ln_bf = (unsigned short*)ws;
    unsigned short* a1      = (unsigned short*)(ws + 25165824);
    float* h_rnn     = (float*)(ws + 150994944);
    float* energy_ws = (float*)(ws + 201326592);
    int*   idx       = (int*)(ws + 201392128);
    int*   pos       = (int*)(ws + 201424896);
    unsigned short* qkv_w_b  = (unsigned short*)(ws + 201490432);
    unsigned short* proj_w_b = (unsigned short*)(ws + 205029376);
    unsigned short* w1_b     = (unsigned short*)(ws + 206209024);
    unsigned short* w2_b     = (unsigned short*)(ws + 210927616);
    int*   cnt       = (int*)(ws + 215646208);   // 8*2048 ints = 64 KB
    // end: 215,711,744 B

    init_ws<<<64, 256, 0, stream>>>(pos, cnt, out);
    cvt_bf16<<<2048, 256, 0, stream>>>(qkv_w, qkv_w_b, G3 * Cz);
    cvt_bf16<<<2048, 256, 0, stream>>>(proj_w, proj_w_b, Cz * Cz);
    cvt_bf16<<<2048, 256, 0, stream>>>(ffn_w1, w1_b, DFF * Cz);
    cvt_bf16<<<2048, 256, 0, stream>>>(ffn_w2, w2_b, Cz * DFF);

    gemm_f32_nt<<<dim3(G3 / 128, MTOK / 128), 256, 0, stream>>>(x, W_ih, b_ih, xi,
                                                                MTOK, G3, Cz);
    gru_scan<<<GRU_WGS, 256, 0, stream>>>(xi, W_hh, b_hh, h_rnn, cnt);

    gate_energy<<<MTOK / 4, 256, 0, stream>>>(h_rnn, gw1, gb1, gw2, gb2, energy_ws, out);
    topk_kernel<<<Bz, 256, 0, stream>>>(energy_ws, idx);
    scatter_pos<<<MSEL / 256, 256, 0, stream>>>(idx, pos);
    gather_sel<<<MSEL * 192 / 256, 256, 0, stream>>>(h_rnn, idx, x_sel);

    gemm_bf16<1><<<dim3(G3 / 128, MSEL / 128), 256, 0, stream>>>(
        x_sel, qkv_w_b, qkv_b, nullptr, qkvb, nullptr, MSEL, G3, Cz);
    flash_attn<<<dim3(16, Bz * Hz), 256, 0, stream>>>(qkvb, y_rows);
    gemm_bf16<0><<<dim3(Cz / 128, MSEL / 128), 256, 0, stream>>>(
        y_rows, proj_w_b, proj_b, proj_out, nullptr, nullptr, MSEL, Cz, Cz);
    ln_fuse<<<MTOK / 4, 256, 0, stream>>>(h_rnn, proj_out, pos, energy_ws, ln_g, ln_b,
                                          h_ln_bf);
    gemm_bf16<2><<<dim3(DFF / 128, MTOK / 128), 256, 0, stream>>>(
        h_ln_bf, w1_b, ffn_b1, nullptr, a1, nullptr, MTOK, DFF, Cz);
    gemm_bf16<3><<<dim3(Cz / 128, MTOK / 128), 256, 0, stream>>>(
        a1, w2_b, ffn_b2, out, nullptr, h_rnn, MTOK, Cz, DFF);
}